// Round 4
// baseline (121.723 us; speedup 1.0000x reference)
//
#include <hip/hip_runtime.h>

// MMD over persistence diagrams, RBF kernel, WIDTH=1, DECAY=1.
// out = sum_b weights[b]/ns[b]^2 * (S_XX - 2 S_XY + S_YY)
// S_AB = sum_{n,m} exp(-||a_n-b_m||^2) * wa_n * wb_m,
// points (birth,death)->(x=birth, l=death-birth), w = l.
//
// R3: symmetric terms computed as strict-lower-triangle * 2 + diag(sum w^2):
// 134M pairs instead of 201M. Single fused kernel, 16 parts x 64 batches;
// per-part ~512 pairs/thread; strip(64)-tiled LDS broadcast with software
// prefetch. Prep pre-scales points: (sx,sy,h,w) with
// t = sx_a*sx_b + sy_a*sy_b + h_a + h_b = -log2e*d^2, K = exp2(t).

#define LOG2E_F  1.44269504088896340736f
#define SQRT2C_F 1.69864360213614f     // sqrt(2*log2(e))

struct __align__(16) P4 { float sx, sy, h, w; };

#define NSLOT 64
#define TPB   256
#define SW    64      // column strip width

#define ACC_BYTES (NSLOT * 8)
#define PTS_OFF   (ACC_BYTES + 16)

// ---------------- prep ----------------
__global__ void prep_kernel(const float* __restrict__ X, const float* __restrict__ Y,
                            P4* __restrict__ PX, P4* __restrict__ PY,
                            int nx_total, int ny_total, double* __restrict__ acc) {
    int i = blockIdx.x * blockDim.x + threadIdx.x;
    if (i < NSLOT) acc[i] = 0.0;
    if (i < nx_total) {
        float2 bd = ((const float2*)X)[i];
        float x = bd.x, l = bd.y - bd.x;
        P4 p; p.sx = SQRT2C_F * x; p.sy = SQRT2C_F * l;
        p.h = -LOG2E_F * fmaf(x, x, l * l); p.w = l;
        PX[i] = p;
    }
    if (i < ny_total) {
        float2 bd = ((const float2*)Y)[i];
        float x = bd.x, l = bd.y - bd.x;
        P4 p; p.sx = SQRT2C_F * x; p.sy = SQRT2C_F * l;
        p.h = -LOG2E_F * fmaf(x, x, l * l); p.w = l;
        PY[i] = p;
    }
}

// ---------------- main (fixed shape N=M=1024) ----------------
// part 0..3:  XX sym, strip-group = part
// part 4..7:  YY sym, strip-group = part-4
// part 8..15: XY rect, strip-group = part-8 (2 strips each)
__global__ __launch_bounds__(TPB) void mmd_main(
    const P4* __restrict__ PXall, const P4* __restrict__ PYall,
    const float* __restrict__ weights, const float* __restrict__ ns,
    double* __restrict__ acc) {

    const int b    = blockIdx.y;
    const int part = blockIdx.x;
    const int tid  = threadIdx.x;

    __shared__ P4 tile[SW];
    __shared__ double redbuf[TPB / 64];

    const P4* __restrict__ PX = PXall + (size_t)b * 1024;
    const P4* __restrict__ PY = PYall + (size_t)b * 1024;

    float thread_val = 0.0f;

    if (part < 8) {
        // ---- symmetric term: strict lower triangle (m < n), doubled ----
        const int sg = part & 3;                       // strips sg, sg+4, sg+8, sg+12
        const P4* __restrict__ A = (part < 4) ? PX : PY;

        // row pairing -> uniform ~2046/4 cols per thread; all wave row-ranges 64-aligned
        int rown[4];
        rown[0] = tid; rown[1] = 1023 - tid; rown[2] = 256 + tid; rown[3] = 767 - tid;

        float asx[4], asy[4], ah[4], aw[4], s[4];
        #pragma unroll
        for (int r = 0; r < 4; ++r) {
            P4 a = A[rown[r]];
            asx[r] = a.sx; asy[r] = a.sy; ah[r] = a.h; aw[r] = a.w;
            s[r] = 0.0f;
        }

        P4 cur;
        if (tid < SW) cur = A[sg * SW + tid];
        #pragma unroll 1
        for (int k = 0; k < 4; ++k) {
            const int sc = (sg + 4 * k) * SW;
            __syncthreads();
            if (tid < SW) tile[tid] = cur;
            __syncthreads();
            if (k < 3 && tid < SW) cur = A[(sg + 4 * (k + 1)) * SW + tid];  // prefetch

            #pragma unroll
            for (int r = 0; r < 4; ++r) {
                const int kcap = rown[r] - sc;       // active cols in strip: m_local < kcap
                if (kcap <= 0) continue;             // wave-uniform in practice (64-aligned)
                float ss = s[r];
                if (kcap >= SW) {                    // full strip — hot path
                    #pragma unroll 8
                    for (int m = 0; m < SW; ++m) {
                        P4 p = tile[m];
                        float t = fmaf(asx[r], p.sx, fmaf(asy[r], p.sy, ah[r] + p.h));
                        ss = fmaf(__builtin_amdgcn_exp2f(t), p.w, ss);
                    }
                } else {                             // boundary tile (~3% of pairs)
                    #pragma unroll 8
                    for (int m = 0; m < SW; ++m) {
                        P4 p = tile[m];
                        float wsel = (m < kcap) ? p.w : 0.0f;
                        float t = fmaf(asx[r], p.sx, fmaf(asy[r], p.sy, ah[r] + p.h));
                        ss = fmaf(__builtin_amdgcn_exp2f(t), wsel, ss);
                    }
                }
                s[r] = ss;
            }
        }
        float tv = 0.0f;
        #pragma unroll
        for (int r = 0; r < 4; ++r) tv = fmaf(aw[r], s[r], tv);
        tv *= 2.0f;                                  // off-diagonal doubling
        if (sg == 0) {                               // diagonal K=1: + sum w^2 (once)
            #pragma unroll
            for (int r = 0; r < 4; ++r) tv = fmaf(aw[r], aw[r], tv);
        }
        thread_val = tv;
    } else {
        // ---- XY rectangle, sign -2 ----
        const int sg = part - 8;                     // strips 2sg, 2sg+1 over PY
        float asx[4], asy[4], ah[4], aw[4], s[4];
        #pragma unroll
        for (int r = 0; r < 4; ++r) {
            P4 a = PX[tid + 256 * r];
            asx[r] = a.sx; asy[r] = a.sy; ah[r] = a.h; aw[r] = a.w;
            s[r] = 0.0f;
        }
        P4 cur;
        if (tid < SW) cur = PY[(2 * sg) * SW + tid];
        #pragma unroll 1
        for (int k = 0; k < 2; ++k) {
            __syncthreads();
            if (tid < SW) tile[tid] = cur;
            __syncthreads();
            if (k < 1 && tid < SW) cur = PY[(2 * sg + 1) * SW + tid];  // prefetch

            #pragma unroll
            for (int r = 0; r < 4; ++r) {
                float ss = s[r];
                #pragma unroll 8
                for (int m = 0; m < SW; ++m) {
                    P4 p = tile[m];
                    float t = fmaf(asx[r], p.sx, fmaf(asy[r], p.sy, ah[r] + p.h));
                    ss = fmaf(__builtin_amdgcn_exp2f(t), p.w, ss);
                }
                s[r] = ss;
            }
        }
        float tv = 0.0f;
        #pragma unroll
        for (int r = 0; r < 4; ++r) tv = fmaf(aw[r], s[r], tv);
        thread_val = -2.0f * tv;
    }

    // ---- block reduction in double ----
    double v = (double)thread_val;
    #pragma unroll
    for (int off = 32; off > 0; off >>= 1) v += __shfl_down(v, off, 64);
    if ((tid & 63) == 0) redbuf[tid >> 6] = v;
    __syncthreads();
    if (tid == 0) {
        double tot = (redbuf[0] + redbuf[1]) + (redbuf[2] + redbuf[3]);
        double nsb = (double)ns[b];
        atomicAdd(&acc[b], tot * ((double)weights[b] / (nsb * nsb)));
    }
}

// ---------------- generic fallback (R2 structure) for unexpected shapes ----------------
__global__ __launch_bounds__(TPB) void mmd_generic(
    const P4* __restrict__ PXall, const P4* __restrict__ PYall,
    const float* __restrict__ weights, const float* __restrict__ ns,
    int N, int M, double* __restrict__ acc) {

    const int b    = blockIdx.z;
    const int term = blockIdx.y;
    const int seg  = blockIdx.x;

    const P4* __restrict__ A  = (term == 2) ? (PYall + (size_t)b * M) : (PXall + (size_t)b * N);
    const P4* __restrict__ Bp = (term == 0) ? (PXall + (size_t)b * N) : (PYall + (size_t)b * M);
    const int nrows = (term == 2) ? M : N;
    const int mlen  = (term == 0) ? N : M;
    const float sign = (term == 1) ? -2.0f : 1.0f;

    const int mstart = seg * 32;
    const int cnt = (mstart + 32 <= mlen) ? 32 : (mlen > mstart ? mlen - mstart : 0);

    __shared__ P4 tile[32];
    __shared__ double redbuf[TPB / 64];
    if (threadIdx.x < cnt) tile[threadIdx.x] = Bp[mstart + threadIdx.x];
    __syncthreads();

    float thread_val = 0.0f;
    for (int n = threadIdx.x; n < nrows; n += TPB) {
        P4 a = A[n];
        float ss = 0.0f;
        for (int m = 0; m < cnt; ++m) {
            P4 p = tile[m];
            float t = fmaf(a.sx, p.sx, fmaf(a.sy, p.sy, a.h + p.h));
            ss = fmaf(__builtin_amdgcn_exp2f(t), p.w, ss);
        }
        thread_val = fmaf(a.w, ss, thread_val);
    }
    // diagonal correction not needed: generic path computes full rectangles for all terms

    double v = (double)thread_val;
    #pragma unroll
    for (int off = 32; off > 0; off >>= 1) v += __shfl_down(v, off, 64);
    if ((threadIdx.x & 63) == 0) redbuf[threadIdx.x >> 6] = v;
    __syncthreads();
    if (threadIdx.x == 0) {
        double tot = (redbuf[0] + redbuf[1]) + (redbuf[2] + redbuf[3]);
        double nsb = (double)ns[b];
        atomicAdd(&acc[b], (double)sign * tot * ((double)weights[b] / (nsb * nsb)));
    }
}

__global__ void finalize_kernel(const double* __restrict__ acc, float* __restrict__ out) {
    if (threadIdx.x == 0 && blockIdx.x == 0) {
        double total = 0.0;
        #pragma unroll
        for (int i = 0; i < NSLOT; ++i) total += acc[i];
        out[0] = (float)total;
    }
}

extern "C" void kernel_launch(void* const* d_in, const int* in_sizes, int n_in,
                              void* d_out, int out_size, void* d_ws, size_t ws_size,
                              hipStream_t stream) {
    const float* X  = (const float*)d_in[0];
    const float* Y  = (const float*)d_in[1];
    const float* W  = (const float*)d_in[2];
    const float* NS = (const float*)d_in[3];

    const int B = in_sizes[2];
    const int N = in_sizes[0] / (2 * B);
    const int M = in_sizes[1] / (2 * B);

    double* acc = (double*)d_ws;
    P4* PX = (P4*)((char*)d_ws + PTS_OFF);
    P4* PY = PX + (size_t)B * N;

    const int nx_total = B * N;
    const int ny_total = B * M;
    const int prep_total = nx_total > ny_total ? nx_total : ny_total;

    prep_kernel<<<(prep_total + 255) / 256, 256, 0, stream>>>(
        X, Y, PX, PY, nx_total, ny_total, acc);

    if (N == 1024 && M == 1024 && B <= NSLOT) {
        dim3 grid(16, B);
        mmd_main<<<grid, TPB, 0, stream>>>(PX, PY, W, NS, acc);
    } else {
        const int mlen_max = N > M ? N : M;
        dim3 grid((mlen_max + 31) / 32, 3, B);
        mmd_generic<<<grid, TPB, 0, stream>>>(PX, PY, W, NS, N, M, acc);
    }

    finalize_kernel<<<1, 64, 0, stream>>>(acc, (float*)d_out);
}

// Round 5
// 91.825 us; speedup vs baseline: 1.3256x; 1.3256x over previous
//
#include <hip/hip_runtime.h>

// MMD over persistence diagrams, RBF kernel, WIDTH=1, DECAY=1.
// out = sum_b weights[b]/ns[b]^2 * (S_XX - 2 S_XY + S_YY)
// S_AB = sum_{n,m} exp(-||a_n-b_m||^2) * wa_n * wb_m,
// points (birth,death)->(x=birth, l=death-birth), w = l.
//
// R4: symmetric terms as strict-lower-triangle*2 + diag (134M pairs), but
// scheduled for occupancy: 32 parts x 64 batches = 2048 blocks (8/CU,
// 32 waves/CU). Wave-private LDS tiles -> no barriers in the hot path.
// (row-block, strip) classification is wave-uniform and dispatched to
// template-specialized loops so ds_read_b128 is amortized over all active
// rows with no per-pair masking except the diagonal block.
// Prep pre-scales points: t = sx_a*sx_b + sy_a*sy_b + h_a + h_b = -log2e*d^2.

#define LOG2E_F  1.44269504088896340736f
#define SQRT2C_F 1.69864360213614f     // sqrt(2*log2(e))

struct __align__(16) P4 { float sx, sy, h, w; };

#define NSLOT 64
#define TPB   256

#define ACC_BYTES (NSLOT * 8)
#define PTS_OFF   (ACC_BYTES + 16)

// ---------------- prep ----------------
__global__ void prep_kernel(const float* __restrict__ X, const float* __restrict__ Y,
                            P4* __restrict__ PX, P4* __restrict__ PY,
                            int nx_total, int ny_total, double* __restrict__ acc) {
    int i = blockIdx.x * blockDim.x + threadIdx.x;
    if (i < NSLOT) acc[i] = 0.0;
    if (i < nx_total) {
        float2 bd = ((const float2*)X)[i];
        float x = bd.x, l = bd.y - bd.x;
        P4 p; p.sx = SQRT2C_F * x; p.sy = SQRT2C_F * l;
        p.h = -LOG2E_F * fmaf(x, x, l * l); p.w = l;
        PX[i] = p;
    }
    if (i < ny_total) {
        float2 bd = ((const float2*)Y)[i];
        float x = bd.x, l = bd.y - bd.x;
        P4 p; p.sx = SQRT2C_F * x; p.sy = SQRT2C_F * l;
        p.h = -LOG2E_F * fmaf(x, x, l * l); p.w = l;
        PY[i] = p;
    }
}

struct Rows { float asx[4], asy[4], ah[4], aw[4]; };

// full 64-col strip for rows r = RS..3 (all 64 cols active)
template<int RS>
__device__ __forceinline__ void strip_full(const P4* __restrict__ tile,
                                           const Rows& A, float* __restrict__ s) {
    #pragma unroll 4
    for (int m = 0; m < 64; ++m) {
        P4 p = tile[m];
        #pragma unroll
        for (int r = RS; r < 4; ++r) {
            float t = fmaf(A.asx[r], p.sx, fmaf(A.asy[r], p.sy, A.ah[r] + p.h));
            s[r] = fmaf(__builtin_amdgcn_exp2f(t), p.w, s[r]);
        }
    }
}

// diagonal 64x64 block for row r = RD: cols m < kcap (kcap = lane)
template<int RD>
__device__ __forceinline__ void strip_diag(const P4* __restrict__ tile, int kcap,
                                           const Rows& A, float* __restrict__ s) {
    #pragma unroll 4
    for (int m = 0; m < 64; ++m) {
        P4 p = tile[m];
        float wsel = (m < kcap) ? p.w : 0.0f;
        float t = fmaf(A.asx[RD], p.sx, fmaf(A.asy[RD], p.sy, A.ah[RD] + p.h));
        s[RD] = fmaf(__builtin_amdgcn_exp2f(t), wsel, s[RD]);
    }
}

// one 64-col strip j of a symmetric term, for this wave's 4 row-blocks.
// row-block index of row r is rb = 4r + w; full iff rb >= j+1, diag iff rb == j.
__device__ __forceinline__ void do_strip_sym(const P4* __restrict__ tile, int j, int w,
                                             int kcap, const Rows& A, float* __restrict__ s) {
    int d = j + 1 - w;
    int rstart = (d <= 0) ? 0 : ((d + 3) >> 2);
    switch (rstart) {                 // wave-uniform branch
        case 0: strip_full<0>(tile, A, s); break;
        case 1: strip_full<1>(tile, A, s); break;
        case 2: strip_full<2>(tile, A, s); break;
        case 3: strip_full<3>(tile, A, s); break;
        default: break;
    }
    int jd = j - w;
    if (jd >= 0 && jd < 16 && (jd & 3) == 0) {
        switch (jd >> 2) {            // wave-uniform
            case 0: strip_diag<0>(tile, kcap, A, s); break;
            case 1: strip_diag<1>(tile, kcap, A, s); break;
            case 2: strip_diag<2>(tile, kcap, A, s); break;
            case 3: strip_diag<3>(tile, kcap, A, s); break;
        }
    }
}

// ---------------- main (fixed shape N=M=1024) ----------------
// part 0..7:   XX sym, strips {p, 15-p}
// part 8..15:  YY sym, strips {p, 15-p}, p = part-8
// part 16..31: XY rect, strip part-16
__global__ __launch_bounds__(TPB) void mmd_main(
    const P4* __restrict__ PXall, const P4* __restrict__ PYall,
    const float* __restrict__ weights, const float* __restrict__ ns,
    double* __restrict__ acc) {

    const int b    = blockIdx.y;
    const int part = blockIdx.x;
    const int tid  = threadIdx.x;
    const int w    = tid >> 6;
    const int lane = tid & 63;

    __shared__ P4 tiles[4][64];       // wave-private tiles
    __shared__ double redbuf[4];
    P4* tile = tiles[w];

    const P4* __restrict__ PX = PXall + (size_t)b * 1024;
    const P4* __restrict__ PY = PYall + (size_t)b * 1024;

    float thread_val = 0.0f;

    if (part < 16) {
        // ---- symmetric term (XX or YY): strips {p, 15-p}, doubled + diag ----
        const int p = part & 7;
        const P4* __restrict__ A = (part < 8) ? PX : PY;
        const int j0 = p, j1 = 15 - p;

        Rows R; float s[4];
        #pragma unroll
        for (int r = 0; r < 4; ++r) {
            P4 a = A[r * 256 + tid];
            R.asx[r] = a.sx; R.asy[r] = a.sy; R.ah[r] = a.h; R.aw[r] = a.w;
            s[r] = 0.0f;
        }

        P4 c0 = A[j0 * 64 + lane];
        P4 c1 = A[j1 * 64 + lane];    // prefetched during strip-0 compute
        tile[lane] = c0;              // within-wave DS order: no barrier needed
        do_strip_sym(tile, j0, w, lane, R, s);
        tile[lane] = c1;
        do_strip_sym(tile, j1, w, lane, R, s);

        float tv = 0.0f;
        #pragma unroll
        for (int r = 0; r < 4; ++r) tv = fmaf(R.aw[r], s[r], tv);
        tv *= 2.0f;                   // off-diagonal doubling
        if (p == 0) {                 // diagonal K=1 contribution, added once per term
            #pragma unroll
            for (int r = 0; r < 4; ++r) tv = fmaf(R.aw[r], R.aw[r], tv);
        }
        thread_val = tv;
    } else {
        // ---- XY rectangle (sign -2), one 64-col strip of PY ----
        const int sp = part - 16;
        Rows R; float s[4];
        #pragma unroll
        for (int r = 0; r < 4; ++r) {
            P4 a = PX[r * 256 + tid];
            R.asx[r] = a.sx; R.asy[r] = a.sy; R.ah[r] = a.h; R.aw[r] = a.w;
            s[r] = 0.0f;
        }
        tile[lane] = PY[sp * 64 + lane];
        strip_full<0>(tile, R, s);

        float tv = 0.0f;
        #pragma unroll
        for (int r = 0; r < 4; ++r) tv = fmaf(R.aw[r], s[r], tv);
        thread_val = -2.0f * tv;
    }

    // ---- block reduction in double (single barrier) ----
    double v = (double)thread_val;
    #pragma unroll
    for (int off = 32; off > 0; off >>= 1) v += __shfl_down(v, off, 64);
    if (lane == 0) redbuf[w] = v;
    __syncthreads();
    if (tid == 0) {
        double tot = (redbuf[0] + redbuf[1]) + (redbuf[2] + redbuf[3]);
        double nsb = (double)ns[b];
        atomicAdd(&acc[b], tot * ((double)weights[b] / (nsb * nsb)));
    }
}

// ---------------- generic fallback for unexpected shapes ----------------
__global__ __launch_bounds__(TPB) void mmd_generic(
    const P4* __restrict__ PXall, const P4* __restrict__ PYall,
    const float* __restrict__ weights, const float* __restrict__ ns,
    int N, int M, double* __restrict__ acc) {

    const int b    = blockIdx.z;
    const int term = blockIdx.y;
    const int seg  = blockIdx.x;

    const P4* __restrict__ A  = (term == 2) ? (PYall + (size_t)b * M) : (PXall + (size_t)b * N);
    const P4* __restrict__ Bp = (term == 0) ? (PXall + (size_t)b * N) : (PYall + (size_t)b * M);
    const int nrows = (term == 2) ? M : N;
    const int mlen  = (term == 0) ? N : M;
    const float sign = (term == 1) ? -2.0f : 1.0f;

    const int mstart = seg * 32;
    const int cnt = (mstart + 32 <= mlen) ? 32 : (mlen > mstart ? mlen - mstart : 0);

    __shared__ P4 tile[32];
    __shared__ double redbuf[TPB / 64];
    if (threadIdx.x < cnt) tile[threadIdx.x] = Bp[mstart + threadIdx.x];
    __syncthreads();

    float thread_val = 0.0f;
    for (int n = threadIdx.x; n < nrows; n += TPB) {
        P4 a = A[n];
        float ss = 0.0f;
        for (int m = 0; m < cnt; ++m) {
            P4 p = tile[m];
            float t = fmaf(a.sx, p.sx, fmaf(a.sy, p.sy, a.h + p.h));
            ss = fmaf(__builtin_amdgcn_exp2f(t), p.w, ss);
        }
        thread_val = fmaf(a.w, ss, thread_val);
    }

    double v = (double)thread_val;
    #pragma unroll
    for (int off = 32; off > 0; off >>= 1) v += __shfl_down(v, off, 64);
    if ((threadIdx.x & 63) == 0) redbuf[threadIdx.x >> 6] = v;
    __syncthreads();
    if (threadIdx.x == 0) {
        double tot = (redbuf[0] + redbuf[1]) + (redbuf[2] + redbuf[3]);
        double nsb = (double)ns[b];
        atomicAdd(&acc[b], (double)sign * tot * ((double)weights[b] / (nsb * nsb)));
    }
}

__global__ void finalize_kernel(const double* __restrict__ acc, float* __restrict__ out) {
    if (threadIdx.x == 0 && blockIdx.x == 0) {
        double total = 0.0;
        #pragma unroll
        for (int i = 0; i < NSLOT; ++i) total += acc[i];
        out[0] = (float)total;
    }
}

extern "C" void kernel_launch(void* const* d_in, const int* in_sizes, int n_in,
                              void* d_out, int out_size, void* d_ws, size_t ws_size,
                              hipStream_t stream) {
    const float* X  = (const float*)d_in[0];
    const float* Y  = (const float*)d_in[1];
    const float* W  = (const float*)d_in[2];
    const float* NS = (const float*)d_in[3];

    const int B = in_sizes[2];
    const int N = in_sizes[0] / (2 * B);
    const int M = in_sizes[1] / (2 * B);

    double* acc = (double*)d_ws;
    P4* PX = (P4*)((char*)d_ws + PTS_OFF);
    P4* PY = PX + (size_t)B * N;

    const int nx_total = B * N;
    const int ny_total = B * M;
    const int prep_total = nx_total > ny_total ? nx_total : ny_total;

    prep_kernel<<<(prep_total + 255) / 256, 256, 0, stream>>>(
        X, Y, PX, PY, nx_total, ny_total, acc);

    if (N == 1024 && M == 1024 && B <= NSLOT) {
        dim3 grid(32, B);
        mmd_main<<<grid, TPB, 0, stream>>>(PX, PY, W, NS, acc);
    } else {
        const int mlen_max = N > M ? N : M;
        dim3 grid((mlen_max + 31) / 32, 3, B);
        mmd_generic<<<grid, TPB, 0, stream>>>(PX, PY, W, NS, N, M, acc);
    }

    finalize_kernel<<<1, 64, 0, stream>>>(acc, (float*)d_out);
}